// Round 11
// baseline (649.899 us; speedup 1.0000x reference)
//
#include <hip/hip_runtime.h>
#include <cstdint>
#include <cstddef>

#define S_LEN 2048
#define BATCH 2
#define DMODEL 1024
#define NH 16
#define NKV 4
#define HDIM 64
#define NTOK 4096
#define IDIM 3584
#define NEXP 4
#define WINSZ 512
#define EPSV 1e-5f
#define LIMV 7.0f
// padded concat rows: experts (each seg padded to 256, sum<=8960) + shared 4096
#define CATMAX 13056

typedef unsigned short u16;
typedef unsigned int u32;
typedef __bf16 bf16x8 __attribute__((ext_vector_type(8)));
typedef float f32x4 __attribute__((ext_vector_type(4)));
typedef u32 u32x4 __attribute__((ext_vector_type(4)));
typedef u16 u16x4 __attribute__((ext_vector_type(4)));

__device__ __forceinline__ u16 f2b(float f) {
  union { float f; u32 u; } v; v.f = f;
  return (u16)((v.u + 0x7fffu + ((v.u >> 16) & 1u)) >> 16);
}
__device__ __forceinline__ float b2f(u16 h) {
  union { u32 u; float f; } v; v.u = ((u32)h) << 16; return v.f;
}
__device__ __forceinline__ float wave_sum(float x) {
#pragma unroll
  for (int o = 32; o > 0; o >>= 1) x += __shfl_xor(x, o);
  return x;
}
// async global->LDS, 16B per lane; LDS dest is wave-uniform base + lane*16
__device__ __forceinline__ void gld16(const void* g, void* l) {
  __builtin_amdgcn_global_load_lds(
      (const __attribute__((address_space(1))) u32*)g,
      (__attribute__((address_space(3))) u32*)l, 16, 0, 0);
}
// bijective XCD-aware block relabel (m204): contiguous swz chunks per XCD
__device__ __forceinline__ int xcd_swz(int id, int nwg) {
  int q = nwg >> 3, rr = nwg & 7;
  int xcd = id & 7, j = id >> 3;
  return (xcd < rr ? xcd * (q + 1) : rr * (q + 1) + (xcd - rr) * q) + j;
}

// ---------------- init ----------------
__global__ void k_init(int* cnt) {
  if (threadIdx.x < NEXP) cnt[threadIdx.x] = 0;
}

// ---------------- weight conversion (fp32 -> bf16, optionally split hi/lo) ----
struct CvtArgs {
  const float* src[10];
  u16* dh[10];
  u16* dl[10];
  int n4[10];
};
__global__ __launch_bounds__(256) void k_convert(CvtArgs a) {
  int ai = blockIdx.y;
  const f32x4* s = (const f32x4*)a.src[ai];
  u16* dh = a.dh[ai];
  u16* dl = a.dl[ai];
  int n4 = a.n4[ai];
  for (int i = blockIdx.x * 256 + threadIdx.x; i < n4; i += gridDim.x * 256) {
    f32x4 v = s[i];
    u16x4 h;
    h.x = f2b(v.x); h.y = f2b(v.y); h.z = f2b(v.z); h.w = f2b(v.w);
    ((u16x4*)dh)[i] = h;
    if (dl) {
      u16x4 lo;
      lo.x = f2b(v.x - b2f(h.x)); lo.y = f2b(v.y - b2f(h.y));
      lo.z = f2b(v.z - b2f(h.z)); lo.w = f2b(v.w - b2f(h.w));
      ((u16x4*)dl)[i] = lo;
    }
  }
}

// ---------------- rms over D=1024, write split bf16 ----------------
__global__ __launch_bounds__(256) void k_rms_split(const float* __restrict__ x,
                                                   const float* __restrict__ w,
                                                   u16* __restrict__ oh, u16* __restrict__ ol) {
  int row = blockIdx.x;
  int t = threadIdx.x;
  const f32x4* xr = (const f32x4*)(x + (size_t)row * DMODEL);
  f32x4 v = xr[t];
  float ss = v.x * v.x + v.y * v.y + v.z * v.z + v.w * v.w;
  ss = wave_sum(ss);
  __shared__ float red[4];
  int wid = t >> 6;
  if ((t & 63) == 0) red[wid] = ss;
  __syncthreads();
  float tot = red[0] + red[1] + red[2] + red[3];
  float r = rsqrtf(tot * (1.0f / DMODEL) + EPSV);
  f32x4 wv = ((const f32x4*)w)[t];
  float y0 = v.x * r * wv.x, y1 = v.y * r * wv.y, y2 = v.z * r * wv.z, y3 = v.w * r * wv.w;
  u16x4 h; h.x = f2b(y0); h.y = f2b(y1); h.z = f2b(y2); h.w = f2b(y3);
  u16x4 lo; lo.x = f2b(y0 - b2f(h.x)); lo.y = f2b(y1 - b2f(h.y));
  lo.z = f2b(y2 - b2f(h.z)); lo.w = f2b(y3 - b2f(h.w));
  ((u16x4*)(oh + (size_t)row * DMODEL))[t] = h;
  ((u16x4*)(ol + (size_t)row * DMODEL))[t] = lo;
}

// ---------------- per-head rms + rope on q/k, split bf16 out; v split too ----
__global__ __launch_bounds__(256) void k_qkprep(const float* __restrict__ qkv,
                                                const float* __restrict__ cosb,
                                                const float* __restrict__ sinb,
                                                const float* __restrict__ qw,
                                                const float* __restrict__ kw,
                                                u16* __restrict__ qhh, u16* __restrict__ qll,
                                                u16* __restrict__ khh, u16* __restrict__ kll,
                                                u16* __restrict__ vhh, u16* __restrict__ vll) {
  int t = blockIdx.x;  // token
  int b = t / S_LEN, s = t - b * S_LEN;
  int wid = threadIdx.x >> 6, l = threadIdx.x & 63;
  const float* row = qkv + (size_t)t * 1536;
  float c = cosb[s * 64 + l], sn = sinb[s * 64 + l];
#pragma unroll
  for (int ii = 0; ii < 6; ii++) {
    int u = wid + 4 * ii;
    if (u < 16) {
      float v = row[u * 64 + l];
      float ss = wave_sum(v * v);
      float r = rsqrtf(ss * (1.0f / 64.0f) + EPSV);
      float vn = v * r * qw[l];
      float p = __shfl_xor(vn, 32);
      float o = (l < 32) ? (vn * c - p * sn) : (vn * c + p * sn);
      o *= 0.125f;  // 1/sqrt(HD) folded into q
      size_t base = (((size_t)(b * NH + u)) * S_LEN + s) * 64 + l;
      u16 hi = f2b(o);
      qhh[base] = hi; qll[base] = f2b(o - b2f(hi));
    } else if (u < 20) {
      int kv = u - 16;
      float v = row[1024 + kv * 64 + l];
      float ss = wave_sum(v * v);
      float r = rsqrtf(ss * (1.0f / 64.0f) + EPSV);
      float vn = v * r * kw[l];
      float p = __shfl_xor(vn, 32);
      float o = (l < 32) ? (vn * c - p * sn) : (vn * c + p * sn);
      size_t base = (((size_t)(b * NKV + kv)) * S_LEN + s) * 64 + l;
      u16 hi = f2b(o);
      khh[base] = hi; kll[base] = f2b(o - b2f(hi));
    } else {
      int kv = u - 20;
      float v = row[1280 + kv * 64 + l];
      size_t base = (((size_t)(b * NKV + kv)) * S_LEN + s) * 64 + l;
      u16 hi = f2b(v);
      vhh[base] = hi; vll[base] = f2b(v - b2f(hi));
    }
  }
}

// ---------------- transpose V: [g][s][64] -> [g][64][s] (bf16 hi/lo) --------
__global__ __launch_bounds__(256) void k_vtrans(const u16* __restrict__ vh,
                                                const u16* __restrict__ vl,
                                                u16* __restrict__ vth, u16* __restrict__ vtl) {
  int kb = blockIdx.x;  // key block of 128
  int gg = blockIdx.y;  // b*4+kv
  __shared__ u16 Th[128 * 64], Tl[128 * 64];
  int t = threadIdx.x;
  const u16* sh = vh + (((size_t)gg * S_LEN) + kb * 128) * 64;
  const u16* sl = vl + (((size_t)gg * S_LEN) + kb * 128) * 64;
#pragma unroll
  for (int p = 0; p < 8; p++) {
    int idx = p * 256 + t;
    int key = idx >> 4, dq = idx & 15;
    u16x4 a = *(const u16x4*)(sh + key * 64 + dq * 4);
    u16x4 bb = *(const u16x4*)(sl + key * 64 + dq * 4);
    int off = key * 128 + ((dq * 8) ^ ((key & 7) << 4));
    *(u16x4*)((char*)Th + off) = a;
    *(u16x4*)((char*)Tl + off) = bb;
  }
  __syncthreads();
  int d = t >> 2, kq = t & 3;
  u16 outh[32], outl[32];
#pragma unroll
  for (int jj = 0; jj < 32; jj++) {
    int key = kq * 32 + jj;
    int off = key * 128 + ((d * 2) ^ ((key & 7) << 4));
    outh[jj] = *(const u16*)((const char*)Th + off);
    outl[jj] = *(const u16*)((const char*)Tl + off);
  }
  u16* dsth = vth + (((size_t)gg * 64) + d) * S_LEN + kb * 128 + kq * 32;
  u16* dstl = vtl + (((size_t)gg * 64) + d) * S_LEN + kb * 128 + kq * 32;
#pragma unroll
  for (int q4 = 0; q4 < 8; q4++) {
    u16x4 a = {outh[q4 * 4], outh[q4 * 4 + 1], outh[q4 * 4 + 2], outh[q4 * 4 + 3]};
    u16x4 bb = {outl[q4 * 4], outl[q4 * 4 + 1], outl[q4 * 4 + 2], outl[q4 * 4 + 3]};
    *(u16x4*)(dsth + q4 * 4) = a;
    *(u16x4*)(dstl + q4 * 4) = bb;
  }
}

// ---------------- MFMA flash attention, split-precision ----------------
__global__ __launch_bounds__(256) void k_attn_mfma(
    const u16* __restrict__ qhp, const u16* __restrict__ qlp,
    const u16* __restrict__ khp, const u16* __restrict__ klp,
    const u16* __restrict__ vthp, const u16* __restrict__ vtlp,
    const float* __restrict__ sinks,
    u16* __restrict__ oh, u16* __restrict__ ol) {
  int qt = blockIdx.x;   // 0..31
  int bh = blockIdx.y;   // b*16+h
  int h = bh & 15, b = bh >> 4;
  int kvg = b * NKV + (h >> 2);
  int qbase = qt * 64;
  int t = threadIdx.x, w = t >> 6, l = t & 63;
  int g = l >> 4, li = l & 15;

  __shared__ u16 Qh[4096], Ql[4096], Kh[4096], Kl[4096], Vh[4096], Vl[4096];
  __shared__ u16 Ph[4][1024], Pl[4][1024];

  {
    const u16* sh = qhp + (((size_t)bh * S_LEN) + qbase) * 64;
    const u16* sl = qlp + (((size_t)bh * S_LEN) + qbase) * 64;
#pragma unroll
    for (int p = 0; p < 2; p++) {
      int idx = p * 256 + t;
      int row = idx >> 3, seg = idx & 7;
      u32x4 a = *(const u32x4*)(sh + row * 64 + seg * 8);
      u32x4 bb = *(const u32x4*)(sl + row * 64 + seg * 8);
      int off = row * 128 + ((seg * 16) ^ ((row & 7) << 4));
      *(u32x4*)((char*)Qh + off) = a;
      *(u32x4*)((char*)Ql + off) = bb;
    }
  }

  float m_[4], lsum[4];
  f32x4 accv[4];
  float sk = sinks[h];
#pragma unroll
  for (int j = 0; j < 4; j++) { m_[j] = sk; lsum[j] = 1.0f; }
#pragma unroll
  for (int nt = 0; nt < 4; nt++) accv[nt] = (f32x4){0.f, 0.f, 0.f, 0.f};

  int j0s = qbase - WINSZ; if (j0s < 0) j0s = 0;
  const u16* khb = khp + ((size_t)kvg * S_LEN) * 64;
  const u16* klb = klp + ((size_t)kvg * S_LEN) * 64;
  const u16* vthb = vthp + ((size_t)kvg * 64) * S_LEN;
  const u16* vtlb = vtlp + ((size_t)kvg * 64) * S_LEN;

  for (int j0 = j0s; j0 <= qbase; j0 += 64) {
    __syncthreads();
#pragma unroll
    for (int p = 0; p < 2; p++) {
      int idx = p * 256 + t;
      int row = idx >> 3, seg = idx & 7;
      int off = row * 128 + ((seg * 16) ^ ((row & 7) << 4));
      *(u32x4*)((char*)Kh + off) = *(const u32x4*)(khb + ((size_t)(j0 + row)) * 64 + seg * 8);
      *(u32x4*)((char*)Kl + off) = *(const u32x4*)(klb + ((size_t)(j0 + row)) * 64 + seg * 8);
      *(u32x4*)((char*)Vh + off) = *(const u32x4*)(vthb + (size_t)row * S_LEN + j0 + seg * 8);
      *(u32x4*)((char*)Vl + off) = *(const u32x4*)(vtlb + (size_t)row * S_LEN + j0 + seg * 8);
    }
    __syncthreads();

    f32x4 S[4];
#pragma unroll
    for (int nt = 0; nt < 4; nt++) S[nt] = (f32x4){0.f, 0.f, 0.f, 0.f};
#pragma unroll
    for (int ks = 0; ks < 2; ks++) {
      int arow = w * 16 + li;
      int coff = ks * 64 + g * 16;
      int ao = arow * 128 + (coff ^ ((arow & 7) << 4));
      bf16x8 qah = *(const bf16x8*)((char*)Qh + ao);
      bf16x8 qal = *(const bf16x8*)((char*)Ql + ao);
#pragma unroll
      for (int nt = 0; nt < 4; nt++) {
        int brow = nt * 16 + li;
        int bo = brow * 128 + (coff ^ ((brow & 7) << 4));
        bf16x8 kbh = *(const bf16x8*)((char*)Kh + bo);
        bf16x8 kbl = *(const bf16x8*)((char*)Kl + bo);
        S[nt] = __builtin_amdgcn_mfma_f32_16x16x32_bf16(qah, kbh, S[nt], 0, 0, 0);
        S[nt] = __builtin_amdgcn_mfma_f32_16x16x32_bf16(qah, kbl, S[nt], 0, 0, 0);
        S[nt] = __builtin_amdgcn_mfma_f32_16x16x32_bf16(qal, kbh, S[nt], 0, 0, 0);
      }
    }

    float scj[4];
#pragma unroll
    for (int j = 0; j < 4; j++) {
      int q = qbase + w * 16 + g * 4 + j;
      float sv[4];
      float mx = -1e30f;
#pragma unroll
      for (int nt = 0; nt < 4; nt++) {
        int key = j0 + nt * 16 + li;
        bool ok = (key <= q) && (key > q - WINSZ);
        sv[nt] = ok ? S[nt][j] : -1e30f;
        mx = fmaxf(mx, sv[nt]);
      }
#pragma unroll
      for (int o = 1; o < 16; o <<= 1) mx = fmaxf(mx, __shfl_xor(mx, o));
      float mn = fmaxf(m_[j], mx);
      float sc = __expf(m_[j] - mn);
      float ps = 0.f;
      float pv[4];
#pragma unroll
      for (int nt = 0; nt < 4; nt++) { pv[nt] = __expf(sv[nt] - mn); ps += pv[nt]; }
#pragma unroll
      for (int o = 1; o < 16; o <<= 1) ps += __shfl_xor(ps, o);
      lsum[j] = lsum[j] * sc + ps;
      m_[j] = mn;
      scj[j] = sc;
      int prow = g * 4 + j;
#pragma unroll
      for (int nt = 0; nt < 4; nt++) {
        int pb = prow * 128 + ((nt * 32 + li * 2) ^ ((prow & 7) << 4));
        u16 hi = f2b(pv[nt]);
        *(u16*)((char*)Ph[w] + pb) = hi;
        *(u16*)((char*)Pl[w] + pb) = f2b(pv[nt] - b2f(hi));
      }
    }
#pragma unroll
    for (int nt = 0; nt < 4; nt++) {
      f32x4 a = accv[nt];
      a[0] *= scj[0]; a[1] *= scj[1]; a[2] *= scj[2]; a[3] *= scj[3];
      accv[nt] = a;
    }

#pragma unroll
    for (int ks = 0; ks < 2; ks++) {
      int coff = ks * 64 + g * 16;
      int pb = li * 128 + (coff ^ ((li & 7) << 4));
      bf16x8 pah = *(const bf16x8*)((char*)Ph[w] + pb);
      bf16x8 pal = *(const bf16x8*)((char*)Pl[w] + pb);
#pragma unroll
      for (int nt = 0; nt < 4; nt++) {
        int vrow = nt * 16 + li;
        int vo = vrow * 128 + (coff ^ ((vrow & 7) << 4));
        bf16x8 vbh = *(const bf16x8*)((char*)Vh + vo);
        bf16x8 vbl = *(const bf16x8*)((char*)Vl + vo);
        accv[nt] = __builtin_amdgcn_mfma_f32_16x16x32_bf16(pah, vbh, accv[nt], 0, 0, 0);
        accv[nt] = __builtin_amdgcn_mfma_f32_16x16x32_bf16(pah, vbl, accv[nt], 0, 0, 0);
        accv[nt] = __builtin_amdgcn_mfma_f32_16x16x32_bf16(pal, vbh, accv[nt], 0, 0, 0);
      }
    }
  }

  float inv[4];
#pragma unroll
  for (int j = 0; j < 4; j++) inv[j] = 1.0f / lsum[j];
#pragma unroll
  for (int nt = 0; nt < 4; nt++) {
#pragma unroll
    for (int j = 0; j < 4; j++) {
      float o = accv[nt][j] * inv[j];
      int token = b * S_LEN + qbase + w * 16 + g * 4 + j;
      size_t off = (size_t)token * (NH * HDIM) + h * 64 + nt * 16 + li;
      u16 hi = f2b(o);
      oh[off] = hi;
      ol[off] = f2b(o - b2f(hi));
    }
  }
}

// ---------------- routing part 1: rms(h1) -> mb bf16 + 4 gate logits --------
__global__ __launch_bounds__(256) void k_routing1(const float* __restrict__ h1,
                                                  const float* __restrict__ pw,
                                                  const float* __restrict__ gw,
                                                  u16* __restrict__ mb,
                                                  float* __restrict__ lgbuf) {
  int row = blockIdx.x;
  int t = threadIdx.x;
  int wid = t >> 6;
  const f32x4* xr = (const f32x4*)(h1 + (size_t)row * DMODEL);
  f32x4 v = xr[t];
  float ss = wave_sum(v.x * v.x + v.y * v.y + v.z * v.z + v.w * v.w);
  __shared__ float red[4];
  __shared__ float redp[4][4];
  if ((t & 63) == 0) red[wid] = ss;
  __syncthreads();
  float tot = red[0] + red[1] + red[2] + red[3];
  float r = rsqrtf(tot * (1.0f / DMODEL) + EPSV);
  f32x4 w4 = ((const f32x4*)pw)[t];
  float m0 = v.x * r * w4.x, m1 = v.y * r * w4.y, m2 = v.z * r * w4.z, m3 = v.w * r * w4.w;
  u16x4 hb; hb.x = f2b(m0); hb.y = f2b(m1); hb.z = f2b(m2); hb.w = f2b(m3);
  ((u16x4*)(mb + (size_t)row * DMODEL))[t] = hb;
#pragma unroll
  for (int e = 0; e < NEXP; e++) {
    f32x4 g4 = ((const f32x4*)(gw + (size_t)e * DMODEL))[t];
    float pe = wave_sum(m0 * g4.x + m1 * g4.y + m2 * g4.z + m3 * g4.w);
    if ((t & 63) == 0) redp[wid][e] = pe;
  }
  __syncthreads();
  if (t < NEXP) {
    float lg = redp[0][t] + redp[1][t] + redp[2][t] + redp[3][t];
    lgbuf[(size_t)row * NEXP + t] = lg;
  }
}

// ---------------- routing part 2: top2, weights, per-expert entry lists ------
// idxb entries: token*2 + slot (slot0 = top1, slot1 = top2)
__global__ __launch_bounds__(256) void k_route2(const float* __restrict__ lgbuf,
                                                float* __restrict__ wd,
                                                int* __restrict__ cnt,
                                                int* __restrict__ idxb) {
  __shared__ int lcnt[NEXP], gbase[NEXP];
  int t = threadIdx.x;
  int token = blockIdx.x * 256 + t;
  if (t < NEXP) lcnt[t] = 0;
  __syncthreads();
  f32x4 lgv = ((const f32x4*)lgbuf)[token];
  float lg[4] = {lgv.x, lgv.y, lgv.z, lgv.w};
  int i1 = 0;
#pragma unroll
  for (int e = 1; e < NEXP; e++) if (lg[e] > lg[i1]) i1 = e;
  int i2 = -1;
#pragma unroll
  for (int e = 0; e < NEXP; e++) if (e != i1 && (i2 < 0 || lg[e] > lg[i2])) i2 = e;
  float d = __expf(lg[i2] - lg[i1]);
  float w1 = 1.0f / (1.0f + d);
  float w2 = 1.0f - w1;
  float wrow[4] = {0.f, 0.f, 0.f, 0.f};
  wrow[i1] = w1; wrow[i2] = w2;
  ((f32x4*)wd)[token] = (f32x4){wrow[0], wrow[1], wrow[2], wrow[3]};
  int r1 = atomicAdd(&lcnt[i1], 1);
  int r2 = atomicAdd(&lcnt[i2], 1);
  __syncthreads();
  if (t < NEXP) gbase[t] = atomicAdd(&cnt[t], lcnt[t]);
  __syncthreads();
  idxb[i1 * NTOK + gbase[i1] + r1] = token * 2;
  idxb[i2 * NTOK + gbase[i2] + r2] = token * 2 + 1;
}

// ------- routing part 3: concat list (256-aligned segs) + shared segment -----
// idxcat entry: token*4 + slot, slot in {0,1,2}; -1 = pad
__global__ __launch_bounds__(256) void k_route3(const int* __restrict__ cnt,
                                                const int* __restrict__ idxb,
                                                const float* __restrict__ wd,
                                                int* __restrict__ idxcat,
                                                float* __restrict__ wcat,
                                                int* __restrict__ pref) {
  int i = blockIdx.x * 256 + threadIdx.x;
  int c0 = cnt[0], c1 = cnt[1], c2 = cnt[2], c3 = cnt[3];
  int p1 = (c0 + 255) & ~255;
  int p2 = p1 + ((c1 + 255) & ~255);
  int p3 = p2 + ((c2 + 255) & ~255);
  int p4 = p3 + ((c3 + 255) & ~255);
  int p5 = p4 + NTOK;
  if (i == 0) {
    pref[0] = 0; pref[1] = p1; pref[2] = p2; pref[3] = p3; pref[4] = p4; pref[5] = p5;
  }
  if (i >= CATMAX) return;
  if (i >= p5) { idxcat[i] = -1; wcat[i] = 0.f; return; }
  if (i >= p4) {  // shared segment: all tokens, slot 2, weight 1
    idxcat[i] = (i - p4) * 4 + 2;
    wcat[i] = 1.0f;
    return;
  }
  int e, base, cn;
  if (i < p1) { e = 0; base = 0; cn = c0; }
  else if (i < p2) { e = 1; base = p1; cn = c1; }
  else if (i < p3) { e = 2; base = p2; cn = c2; }
  else { e = 3; base = p3; cn = c3; }
  int j = i - base;
  if (j < cn) {
    int entry = idxb[e * NTOK + j];
    idxcat[i] = (entry >> 1) * 4 + (entry & 1);
    wcat[i] = wd[(size_t)(entry >> 1) * NEXP + e];
  } else {
    idxcat[i] = -1;
    wcat[i] = 0.f;
  }
}

// ========== gate / up GEMM: 256x128, BK=32, 2-buf, 48 KB, gathered A ========
// k256d-proven structure (fat-row 0-conflict LDS, 2 blocks/CU).
// PH=0 (gate): actout[r*IDIM+c] = bf16(min(g, LIMV))
// PH=1 (up):   gm = b2f(actout[..]); actout[..] = bf16(silu(gm)*clip(u,+-7))
template <int PH>
__global__ __launch_bounds__(512, 4) void k256p(
    const u16* __restrict__ A, const u16* __restrict__ Be,
    const int* __restrict__ idxcat, const int* __restrict__ pref,
    u16* __restrict__ actout) {
  __shared__ u16 As[2][256 * 32];   // 32 KB
  __shared__ u16 B1s[2][128 * 32];  // 16 KB
  int nwg = gridDim.x * gridDim.y;
  int swzid = xcd_swz(blockIdx.y * gridDim.x + blockIdx.x, nwg);
  int tn = swzid % gridDim.x, tm = swzid / gridDim.x;
  int Meff = pref[5];
  int r0 = tm * 256;
  if (r0 >= Meff) return;
  int e = (r0 < pref[1]) ? 0 : (r0 < pref[2]) ? 1 : (r0 < pref[3]) ? 2
          : (r0 < pref[4]) ? 3 : 4;
  const u16* B1 = Be + (size_t)e * IDIM * DMODEL;

  int t = threadIdx.x;
  int w = t >> 6, l = t & 63;
  int wm = w >> 2, wn = w & 3;
  int li = l & 15, lh = l >> 4;

  // write-side (inverse fat-row permutation), A: 2 chunks (gathered), B: 1
  int g = (l & 7) ^ (l >> 3);
  int kchunk = g & 3;
  size_t aG[2];
#pragma unroll
  for (int c = 0; c < 2; c++) {
    int rA = c * 64 + w * 8 + (l >> 3) + 128 * (g >> 2);
    int en = idxcat[r0 + rA];
    int row = (en >= 0) ? (en >> 2) : 0;
    aG[c] = (size_t)row * DMODEL + kchunk * 8;
  }
  size_t bG;
  {
    int rB = w * 8 + (l >> 3) + 64 * (g >> 2);
    bG = (size_t)(tn * 128 + rB) * DMODEL + kchunk * 8;
  }
  int wlds = w * 1024;

  // read-side LDS byte bases (XOR fat-row swizzle)
  int abase = li * 128 + (((wm * 4 + lh) ^ (li & 7)) << 4);
  int bbase = ((wn & 1) * 32 + li) * 128 + ((((wn >> 1) * 4 + lh) ^ (li & 7)) << 4);

  f32x4 acc[8][2];
#pragma unroll
  for (int f = 0; f < 8; f++)
#pragma unroll
    for (int cf = 0; cf < 2; cf++) acc[f][cf] = (f32x4){0.f, 0.f, 0.f, 0.f};

  auto stage = [&](int buf, int k0) {
    char* as = (char*)As[buf];
    gld16(A + aG[0] + k0, as + wlds);
    gld16(A + aG[1] + k0, as + 8192 + wlds);
    gld16(B1 + bG + k0, (char*)B1s[buf] + wlds);
  };

  stage(0, 0);
  __syncthreads();

  int NT = DMODEL >> 5;  // 32
  int cur = 0;
  for (int kt = 0; kt < NT; kt++) {
    if (kt + 1 < NT) stage(cur ^ 1, (kt + 1) << 5);
    bf16x8 af[8];
#pragma unroll
    for (int f = 0; f < 8; f++)
      af[f] = *(const bf16x8*)((const char*)As[cur] + abase + f * 2048);
    bf16x8 b1f[2];
#pragma unroll
    for (int cf = 0; cf < 2; cf++)
      b1f[cf] = *(const bf16x8*)((const char*)B1s[cur] + bbase + cf * 2048);
#pragma unroll
    for (int f = 0; f < 8; f++)
#pragma unroll
      for (int cf = 0; cf < 2; cf++)
        acc[f][cf] = __builtin_amdgcn_mfma_f32_16x16x32_bf16(af[f], b1f[cf], acc[f][cf], 0, 0, 0);
    __syncthreads();
    cur ^= 1;
  }

#pragma unroll
  for (int f = 0; f < 8; f++) {
#pragma unroll
    for (int j = 0; j < 4; j++) {
      int r = r0 + wm * 128 + f * 16 + lh * 4 + j;
#pragma unroll
      for (int cf = 0; cf < 2; cf++) {
        int c = tn * 128 + wn * 32 + cf * 16 + li;
        size_t o = (size_t)r * IDIM + c;
        float v = acc[f][cf][j];
        if constexpr (PH == 0) {
          actout[o] = f2b(fminf(v, LIMV));
        } else {
          float gm = b2f(actout[o]);
          float um = fminf(fmaxf(v, -LIMV), LIMV);
          float a = gm / (1.0f + __expf(-gm)) * um;
          actout[o] = f2b(a);
        }
      }
    }
  }
}

// ========== down-proj: 256x128, BK=32, 2-buf, 48 KB LDS (2 blocks/CU) =======
__global__ __launch_bounds__(512, 4) void k256d(
    const u16* __restrict__ A, const u16* __restrict__ B1e,
    const int* __restrict__ idxcat, const float* __restrict__ wcat,
    const int* __restrict__ pref,
    u16* __restrict__ y3) {
  __shared__ u16 As[2][256 * 32];   // 32 KB
  __shared__ u16 B1s[2][128 * 32];  // 16 KB
  int nwg = gridDim.x * gridDim.y;
  int swzid = xcd_swz(blockIdx.y * gridDim.x + blockIdx.x, nwg);
  int tn = swzid % gridDim.x, tm = swzid / gridDim.x;
  int Meff = pref[5];
  int r0 = tm * 256;
  if (r0 >= Meff) return;
  int e = (r0 < pref[1]) ? 0 : (r0 < pref[2]) ? 1 : (r0 < pref[3]) ? 2
          : (r0 < pref[4]) ? 3 : 4;
  const u16* B1 = B1e + (size_t)e * DMODEL * IDIM;

  int t = threadIdx.x;
  int w = t >> 6, l = t & 63;
  int wm = w >> 2, wn = w & 3;
  int li = l & 15, lh = l >> 4;

  int g = (l & 7) ^ (l >> 3);
  int kchunk = g & 3;
  size_t aG[2];
#pragma unroll
  for (int c = 0; c < 2; c++) {
    int rA = c * 64 + w * 8 + (l >> 3) + 128 * (g >> 2);
    aG[c] = (size_t)(r0 + rA) * IDIM + kchunk * 8;
  }
  size_t bG;
  {
    int rB = w * 8 + (l >> 3) + 64 * (g >> 2);
    bG = (size_t)(tn * 128 + rB) * IDIM + kchunk * 8;
  }
  int wlds = w * 1024;

  int abase = li * 128 + (((wm * 4 + lh) ^ (li & 7)) << 4);
  int bbase = ((wn & 1) * 32 + li) * 128 + ((((wn >> 1) * 4 + lh) ^ (li & 7)) << 4);

  f32x4 acc[8][2];
#pragma unroll
  for (int f = 0; f < 8; f++)
#pragma unroll
    for (int cf = 0; cf < 2; cf++) acc[f][cf] = (f32x4){0.f, 0.f, 0.f, 0.f};

  auto stage = [&](int buf, int k0) {
    char* as = (char*)As[buf];
    gld16(A + aG[0] + k0, as + wlds);
    gld16(A + aG[1] + k0, as + 8192 + wlds);
    gld16(B1 + bG + k0, (char*)B1s[buf] + wlds);
  };

  stage(0, 0);
  __syncthreads();

  int NT = IDIM >> 5;  // 112
  int cur = 0;
  for (int kt = 0; kt < NT; kt++) {
    if (kt + 1 < NT) stage(cur ^ 1, (kt + 1) << 5);
    bf16x8 af[8];
#pragma unroll
    for (int f = 0; f < 8; f++)
      af[f] = *(const bf16x8*)((const char*)As[cur] + abase + f * 2048);
    bf16x8 b1f[2];
#pragma unroll
    for (int cf = 0; cf < 2; cf++)
      b1f[cf] = *(const bf16x8*)((const char*)B1s[cur] + bbase + cf * 2048);
#pragma unroll
    for (int f = 0; f < 8; f++)
#pragma unroll
      for (int cf = 0; cf < 2; cf++)
        acc[f][cf] = __builtin_amdgcn_mfma_f32_16x16x32_bf16(af[f], b1f[cf], acc[f][cf], 0, 0, 0);
    __syncthreads();
    cur ^= 1;
  }

#pragma unroll
  for (int f = 0; f < 8; f++) {
#pragma unroll
    for (int j = 0; j < 4; j++) {
      int r = r0 + wm * 128 + f * 16 + lh * 4 + j;
#pragma unroll
      for (int cf = 0; cf < 2; cf++) {
        int c = tn * 128 + wn * 32 + cf * 16 + li;
        int entry = idxcat[r];
        if (entry >= 0) {
          int tok = entry >> 2, slot = entry & 3;
          y3[((size_t)slot * NTOK + tok) * DMODEL + c] = f2b(wcat[r] * acc[f][cf][j]);
        }
      }
    }
  }
}

// ---------------- MFMA GEMM (split precision): C = A @ Bw^T ----------------
// 128x128 tile, BK=32, double-buffered gld16 staging. QKV / WO only.
constexpr int EPI_STORE = 0;  // outF[r*ldc + col0 + c] = v
constexpr int EPI_H1 = 1;     // outF[r*ldc+c] = v + addsrc[r*ldc+c]

template <int EPI>
__global__ __launch_bounds__(256, 2) void k_gemm(
    const u16* __restrict__ Ah, const u16* __restrict__ Al,
    const u16* __restrict__ Bh, const u16* __restrict__ Bl,
    int M, int N, int K, int lda, int ldb,
    float* __restrict__ outF, int ldc, int col0,
    const float* __restrict__ addsrc) {
  __shared__ u16 As[2][2 * 128 * 32];  // per buf: hi (0..8KB) + lo (8..16KB)
  __shared__ u16 Bs[2][2 * 128 * 32];
  int tm = blockIdx.y, tn = blockIdx.x;
  int t = threadIdx.x;
  int w = t >> 6, l = t & 63;
  int wr = w >> 1, wc = w & 1;

  size_t a0 = (size_t)(tm * 128 + (t >> 2)) * lda + (t & 3) * 8;
  size_t a1 = a0 + (size_t)64 * lda;
  size_t b0 = (size_t)(tn * 128 + (t >> 2)) * ldb + (t & 3) * 8;
  size_t b1 = b0 + (size_t)64 * ldb;

  f32x4 acc[4][4];
#pragma unroll
  for (int i = 0; i < 4; i++)
#pragma unroll
    for (int j = 0; j < 4; j++) acc[i][j] = (f32x4){0.f, 0.f, 0.f, 0.f};

  int arow = wr * 64 + (l & 15);
  int brow = wc * 64 + (l & 15);
  int koff = (l >> 4) * 8;

  auto stage = [&](int buf, int k0) {
    char* AsW0 = (char*)As[buf] + w * 1024;
    char* AsW1 = (char*)As[buf] + 4096 + w * 1024;
    char* BsW0 = (char*)Bs[buf] + w * 1024;
    char* BsW1 = (char*)Bs[buf] + 4096 + w * 1024;
    gld16(Ah + a0 + k0, AsW0);
    gld16(Ah + a1 + k0, AsW1);
    gld16(Bh + b0 + k0, BsW0);
    gld16(Bh + b1 + k0, BsW1);
    gld16(Al + a0 + k0, AsW0 + 8192);
    gld16(Al + a1 + k0, AsW1 + 8192);
    gld16(Bl + b0 + k0, BsW0 + 8192);
    gld16(Bl + b1 + k0, BsW1 + 8192);
  };

  stage(0, 0);
  __syncthreads();

  int NT = K >> 5;
  int cur = 0;
  for (int kt = 0; kt < NT; kt++) {
    if (kt + 1 < NT) stage(cur ^ 1, (kt + 1) << 5);
    const u16* Asb = As[cur];
    const u16* Bsb = Bs[cur];
    bf16x8 af[2][4], bf[2][4];
#pragma unroll
    for (int mm = 0; mm < 4; mm++) {
      af[0][mm] = *(const bf16x8*)&Asb[(arow + mm * 16) * 32 + koff];
      bf[0][mm] = *(const bf16x8*)&Bsb[(brow + mm * 16) * 32 + koff];
      af[1][mm] = *(const bf16x8*)&Asb[128 * 32 + (arow + mm * 16) * 32 + koff];
      bf[1][mm] = *(const bf16x8*)&Bsb[128 * 32 + (brow + mm * 16) * 32 + koff];
    }
#pragma unroll
    for (int mi = 0; mi < 4; mi++)
#pragma unroll
      for (int ni = 0; ni < 4; ni++) {
        acc[mi][ni] = __builtin_amdgcn_mfma_f32_16x16x32_bf16(af[0][mi], bf[0][ni], acc[mi][ni], 0, 0, 0);
        acc[mi][ni] = __builtin_amdgcn_mfma_f32_16x16x32_bf16(af[0][mi], bf[1][ni], acc[mi][ni], 0, 0, 0);
        acc[mi][ni] = __builtin_amdgcn_mfma_f32_16x16x32_bf16(af[1][mi], bf[0][ni], acc[mi][ni], 0, 0, 0);
      }
    __syncthreads();
    cur ^= 1;
  }

  int rb = tm * 128 + wr * 64 + ((l >> 4) << 2);
  int cb = tn * 128 + wc * 64 + (l & 15);
#pragma unroll
  for (int mi = 0; mi < 4; mi++) {
#pragma unroll
    for (int j = 0; j < 4; j++) {
      int r = rb + mi * 16 + j;
#pragma unroll
      for (int ni = 0; ni < 4; ni++) {
        int c = cb + ni * 16;
        float v = acc[mi][ni][j];
        if constexpr (EPI == EPI_STORE) {
          outF[(size_t)r * ldc + col0 + c] = v;
        } else {
          size_t o = (size_t)r * ldc + c;
          outF[o] = v + addsrc[o];
        }
      }
    }
  }
}

// ---------------- final: out = h1 + y3[0] + y3[1] + y3[2] ----------------
__global__ __launch_bounds__(256) void k_final(const float* __restrict__ h1,
                                               const u16* __restrict__ y3,
                                               float* __restrict__ out) {
  int i = blockIdx.x * 256 + threadIdx.x;
  f32x4 a = ((const f32x4*)h1)[i];
  u16x4 s0 = ((const u16x4*)y3)[i];
  u16x4 s1 = ((const u16x4*)(y3 + (size_t)NTOK * DMODEL))[i];
  u16x4 s2 = ((const u16x4*)(y3 + (size_t)2 * NTOK * DMODEL))[i];
  f32x4 r = {a.x + b2f(s0.x) + b2f(s1.x) + b2f(s2.x),
             a.y + b2f(s0.y) + b2f(s1.y) + b2f(s2.y),
             a.z + b2f(s0.z) + b2f(s1.z) + b2f(s2.z),
             a.w + b2f(s0.w) + b2f(s1.w) + b2f(s2.w)};
  ((f32x4*)out)[i] = r;
}

// ---------------- host ----------------
extern "C" void kernel_launch(void* const* d_in, const int* in_sizes, int n_in,
                              void* d_out, int out_size, void* d_ws, size_t ws_size,
                              hipStream_t stream) {
  (void)in_sizes; (void)n_in; (void)out_size; (void)ws_size;
  const float* x = (const float*)d_in[0];
  const float* cosb = (const float*)d_in[1];
  const float* sinb = (const float*)d_in[2];
  const float* anw = (const float*)d_in[3];
  const float* pnw = (const float*)d_in[4];
  const float* qnw = (const float*)d_in[5];
  const float* knw = (const float*)d_in[6];
  const float* wq = (const float*)d_in[7];
  const float* wk = (const float*)d_in[8];
  const float* wv = (const float*)d_in[9];
  const float* wo = (const float*)d_in[10];
  const float* sinks = (const float*)d_in[11];
  const float* gw = (const float*)d_in[12];
  const float* egw = (const float*)d_in[13];
  const float* euw = (const float*)d_in[14];
  const float* edw = (const float*)d_in[15];
  const float* sgw = (const float*)d_in[16];
  const float* suw = (const float*)d_in[17];
  const float* sdw = (const float*)d_in[18];
  float* out = (float*)d_out;

  char* ws = (char*)d_ws;
  size_t off = 0;
  auto alloc = [&](size_t bytes) -> char* {
    char* p = ws + off;
    off += (bytes + 255) & ~(size_t)255;
    return p;
  };
  const size_t EW = (size_t)IDIM * DMODEL;  // 3,670,016 elems per expert matrix
  u16* wqkvh = (u16*)alloc((size_t)1536 * 1024 * 2);
  u16* wqkvl = (u16*)alloc((size_t)1536 * 1024 * 2);
  u16* woh = (u16*)alloc(1048576 * 2); u16* wol = (u16*)alloc(1048576 * 2);
  u16* egb5 = (u16*)alloc(5 * EW * 2);   // experts 0..3 + shared at slot 4
  u16* eub5 = (u16*)alloc(5 * EW * 2);
  u16* edb5 = (u16*)alloc(5 * EW * 2);
  float* h1 = (float*)alloc((size_t)NTOK * DMODEL * 4);
  u16* mb = (u16*)alloc((size_t)NTOK * DMODEL * 2);
  u16* y3 = (u16*)alloc((size_t)3 * NTOK * DMODEL * 2);
  float* wdbuf = (float*)alloc((size_t)NTOK * NEXP * 4);
  float* lgbuf = (float*)alloc((size_t)NTOK * NEXP * 4);
  int* cnt = (int*)alloc(256);
  int* idxb = (int*)alloc((size_t)NEXP * NTOK * 4);
  int* idxcat = (int*)alloc((size_t)CATMAX * 4);
  float* wcat = (float*)alloc((size_t)CATMAX * 4);
  int* pref = (int*)alloc(256);
  // big overlapped region (93.6 MB): attention-phase scratch, then MoE acts.
  char* regA = alloc((size_t)CATMAX * IDIM * 2);
  float* qkvb = (float*)regA;
  u16* qh_ = (u16*)(regA + 25165824);
  u16* ql_ = (u16*)(regA + 33554432);
  u16* kh_ = (u16*)(regA + 41943040);
  u16* kl_ = (u16*)(regA + 44040192);
  u16* vh_ = (u16*)(regA + 46137344);
  u16* vl_ = (u16*)(regA + 48234496);
  u16* vth_ = (u16*)(regA + 50331648);
  u16* vtl_ = (u16*)(regA + 52428800);
  u16* hinh = (u16*)(regA + 54525952);
  u16* hinl = (u16*)(regA + 62914560);
  u16* attnh = (u16*)(regA + 71303168);
  u16* attnl = (u16*)(regA + 79691776);
  u16* actcat = (u16*)regA;  // MoE phase: CATMAX x 3584 bf16 (whole region)

  k_init<<<1, 64, 0, stream>>>(cnt);

  CvtArgs ca;
  const float* srcs[10] = {wq, wk, wv, wo, egw, euw, edw, sgw, suw, sdw};
  u16* dhs[10] = {wqkvh, wqkvh + 1048576, wqkvh + 1310720, woh,
                  egb5, eub5, edb5, egb5 + 4 * EW, eub5 + 4 * EW, edb5 + 4 * EW};
  u16* dls[10] = {wqkvl, wqkvl + 1048576, wqkvl + 1310720, wol,
                  nullptr, nullptr, nullptr, nullptr, nullptr, nullptr};
  int ns[10] = {1048576, 262144, 262144, 1048576, 14680064, 14680064, 14680064,
                3670016, 3670016, 3670016};
  for (int i = 0; i < 10; i++) {
    ca.src[i] = srcs[i]; ca.dh[i] = dhs[i]; ca.dl[i] = dls[i]; ca.n4[i] = ns[i] / 4;
  }
  k_convert<<<dim3(2048, 10), 256, 0, stream>>>(ca);

  k_rms_split<<<NTOK, 256, 0, stream>>>(x, anw, hinh, hinl);

  // merged QKV projection (split precision), fp32 into qkvb (ldc=1536)
  k_gemm<EPI_STORE><<<dim3(12, 32), 256, 0, stream>>>(
      hinh, hinl, wqkvh, wqkvl, NTOK, 1536, 1024, 1024, 1024,
      qkvb, 1536, 0, nullptr);

  k_qkprep<<<NTOK, 256, 0, stream>>>(qkvb, cosb, sinb, qnw, knw,
                                     qh_, ql_, kh_, kl_, vh_, vl_);
  k_vtrans<<<dim3(16, 8), 256, 0, stream>>>(vh_, vl_, vth_, vtl_);
  k_attn_mfma<<<dim3(32, 32), 256, 0, stream>>>(qh_, ql_, kh_, kl_, vth_, vtl_,
                                                sinks, attnh, attnl);

  // out-proj + residual -> h1 (split precision)
  k_gemm<EPI_H1><<<dim3(8, 32), 256, 0, stream>>>(
      attnh, attnl, woh, wol, NTOK, 1024, 1024, 1024, 1024,
      h1, 1024, 0, x);

  k_routing1<<<NTOK, 256, 0, stream>>>(h1, pnw, gw, mb, lgbuf);
  k_route2<<<16, 256, 0, stream>>>(lgbuf, wdbuf, cnt, idxb);
  k_route3<<<CATMAX / 256, 256, 0, stream>>>(cnt, idxb, wdbuf, idxcat, wcat, pref);

  // MoE: gate GEMM -> up GEMM (+in-place SwiGLU) -> down GEMM
  k256p<0><<<dim3(IDIM / 128, CATMAX / 256), 512, 0, stream>>>(
      mb, egb5, idxcat, pref, actcat);
  k256p<1><<<dim3(IDIM / 128, CATMAX / 256), 512, 0, stream>>>(
      mb, eub5, idxcat, pref, actcat);
  k256d<<<dim3(DMODEL / 128, CATMAX / 256), 512, 0, stream>>>(
      actcat, edb5, idxcat, wcat, pref, y3);

  k_final<<<4096, 256, 0, stream>>>(h1, y3, out);
}

// Round 12
// 617.043 us; speedup vs baseline: 1.0532x; 1.0532x over previous
//
#include <hip/hip_runtime.h>
#include <cstdint>
#include <cstddef>

#define S_LEN 2048
#define BATCH 2
#define DMODEL 1024
#define NH 16
#define NKV 4
#define HDIM 64
#define NTOK 4096
#define IDIM 3584
#define NEXP 4
#define WINSZ 512
#define EPSV 1e-5f
#define LIMV 7.0f
// padded concat rows: experts (each seg padded to 256, sum<=8960) + shared 4096
#define CATMAX 13056

typedef unsigned short u16;
typedef unsigned int u32;
typedef __bf16 bf16x8 __attribute__((ext_vector_type(8)));
typedef float f32x4 __attribute__((ext_vector_type(4)));
typedef u32 u32x4 __attribute__((ext_vector_type(4)));
typedef u16 u16x4 __attribute__((ext_vector_type(4)));

__device__ __forceinline__ u16 f2b(float f) {
  union { float f; u32 u; } v; v.f = f;
  return (u16)((v.u + 0x7fffu + ((v.u >> 16) & 1u)) >> 16);
}
__device__ __forceinline__ float b2f(u16 h) {
  union { u32 u; float f; } v; v.u = ((u32)h) << 16; return v.f;
}
__device__ __forceinline__ float wave_sum(float x) {
#pragma unroll
  for (int o = 32; o > 0; o >>= 1) x += __shfl_xor(x, o);
  return x;
}
// async global->LDS, 16B per lane; LDS dest is wave-uniform base + lane*16
__device__ __forceinline__ void gld16(const void* g, void* l) {
  __builtin_amdgcn_global_load_lds(
      (const __attribute__((address_space(1))) u32*)g,
      (__attribute__((address_space(3))) u32*)l, 16, 0, 0);
}
// bijective XCD-aware block relabel (m204): contiguous swz chunks per XCD
__device__ __forceinline__ int xcd_swz(int id, int nwg) {
  int q = nwg >> 3, rr = nwg & 7;
  int xcd = id & 7, j = id >> 3;
  return (xcd < rr ? xcd * (q + 1) : rr * (q + 1) + (xcd - rr) * q) + j;
}

// ---------------- init ----------------
__global__ void k_init(int* cnt) {
  if (threadIdx.x < NEXP) cnt[threadIdx.x] = 0;
}

// ---------------- weight conversion (fp32 -> bf16, optionally split hi/lo) ----
struct CvtArgs {
  const float* src[10];
  u16* dh[10];
  u16* dl[10];
  int n4[10];
};
__global__ __launch_bounds__(256) void k_convert(CvtArgs a) {
  int ai = blockIdx.y;
  const f32x4* s = (const f32x4*)a.src[ai];
  u16* dh = a.dh[ai];
  u16* dl = a.dl[ai];
  int n4 = a.n4[ai];
  for (int i = blockIdx.x * 256 + threadIdx.x; i < n4; i += gridDim.x * 256) {
    f32x4 v = s[i];
    u16x4 h;
    h.x = f2b(v.x); h.y = f2b(v.y); h.z = f2b(v.z); h.w = f2b(v.w);
    ((u16x4*)dh)[i] = h;
    if (dl) {
      u16x4 lo;
      lo.x = f2b(v.x - b2f(h.x)); lo.y = f2b(v.y - b2f(h.y));
      lo.z = f2b(v.z - b2f(h.z)); lo.w = f2b(v.w - b2f(h.w));
      ((u16x4*)dl)[i] = lo;
    }
  }
}

// ---------------- rms over D=1024, write split bf16 ----------------
__global__ __launch_bounds__(256) void k_rms_split(const float* __restrict__ x,
                                                   const float* __restrict__ w,
                                                   u16* __restrict__ oh, u16* __restrict__ ol) {
  int row = blockIdx.x;
  int t = threadIdx.x;
  const f32x4* xr = (const f32x4*)(x + (size_t)row * DMODEL);
  f32x4 v = xr[t];
  float ss = v.x * v.x + v.y * v.y + v.z * v.z + v.w * v.w;
  ss = wave_sum(ss);
  __shared__ float red[4];
  int wid = t >> 6;
  if ((t & 63) == 0) red[wid] = ss;
  __syncthreads();
  float tot = red[0] + red[1] + red[2] + red[3];
  float r = rsqrtf(tot * (1.0f / DMODEL) + EPSV);
  f32x4 wv = ((const f32x4*)w)[t];
  float y0 = v.x * r * wv.x, y1 = v.y * r * wv.y, y2 = v.z * r * wv.z, y3 = v.w * r * wv.w;
  u16x4 h; h.x = f2b(y0); h.y = f2b(y1); h.z = f2b(y2); h.w = f2b(y3);
  u16x4 lo; lo.x = f2b(y0 - b2f(h.x)); lo.y = f2b(y1 - b2f(h.y));
  lo.z = f2b(y2 - b2f(h.z)); lo.w = f2b(y3 - b2f(h.w));
  ((u16x4*)(oh + (size_t)row * DMODEL))[t] = h;
  ((u16x4*)(ol + (size_t)row * DMODEL))[t] = lo;
}

// ---------------- per-head rms + rope on q/k, split bf16 out; v split too ----
__global__ __launch_bounds__(256) void k_qkprep(const float* __restrict__ qkv,
                                                const float* __restrict__ cosb,
                                                const float* __restrict__ sinb,
                                                const float* __restrict__ qw,
                                                const float* __restrict__ kw,
                                                u16* __restrict__ qhh, u16* __restrict__ qll,
                                                u16* __restrict__ khh, u16* __restrict__ kll,
                                                u16* __restrict__ vhh, u16* __restrict__ vll) {
  int t = blockIdx.x;  // token
  int b = t / S_LEN, s = t - b * S_LEN;
  int wid = threadIdx.x >> 6, l = threadIdx.x & 63;
  const float* row = qkv + (size_t)t * 1536;
  float c = cosb[s * 64 + l], sn = sinb[s * 64 + l];
#pragma unroll
  for (int ii = 0; ii < 6; ii++) {
    int u = wid + 4 * ii;
    if (u < 16) {
      float v = row[u * 64 + l];
      float ss = wave_sum(v * v);
      float r = rsqrtf(ss * (1.0f / 64.0f) + EPSV);
      float vn = v * r * qw[l];
      float p = __shfl_xor(vn, 32);
      float o = (l < 32) ? (vn * c - p * sn) : (vn * c + p * sn);
      o *= 0.125f;  // 1/sqrt(HD) folded into q
      size_t base = (((size_t)(b * NH + u)) * S_LEN + s) * 64 + l;
      u16 hi = f2b(o);
      qhh[base] = hi; qll[base] = f2b(o - b2f(hi));
    } else if (u < 20) {
      int kv = u - 16;
      float v = row[1024 + kv * 64 + l];
      float ss = wave_sum(v * v);
      float r = rsqrtf(ss * (1.0f / 64.0f) + EPSV);
      float vn = v * r * kw[l];
      float p = __shfl_xor(vn, 32);
      float o = (l < 32) ? (vn * c - p * sn) : (vn * c + p * sn);
      size_t base = (((size_t)(b * NKV + kv)) * S_LEN + s) * 64 + l;
      u16 hi = f2b(o);
      khh[base] = hi; kll[base] = f2b(o - b2f(hi));
    } else {
      int kv = u - 20;
      float v = row[1280 + kv * 64 + l];
      size_t base = (((size_t)(b * NKV + kv)) * S_LEN + s) * 64 + l;
      u16 hi = f2b(v);
      vhh[base] = hi; vll[base] = f2b(v - b2f(hi));
    }
  }
}

// ---------------- transpose V: [g][s][64] -> [g][64][s] (bf16 hi/lo) --------
__global__ __launch_bounds__(256) void k_vtrans(const u16* __restrict__ vh,
                                                const u16* __restrict__ vl,
                                                u16* __restrict__ vth, u16* __restrict__ vtl) {
  int kb = blockIdx.x;  // key block of 128
  int gg = blockIdx.y;  // b*4+kv
  __shared__ u16 Th[128 * 64], Tl[128 * 64];
  int t = threadIdx.x;
  const u16* sh = vh + (((size_t)gg * S_LEN) + kb * 128) * 64;
  const u16* sl = vl + (((size_t)gg * S_LEN) + kb * 128) * 64;
#pragma unroll
  for (int p = 0; p < 8; p++) {
    int idx = p * 256 + t;
    int key = idx >> 4, dq = idx & 15;
    u16x4 a = *(const u16x4*)(sh + key * 64 + dq * 4);
    u16x4 bb = *(const u16x4*)(sl + key * 64 + dq * 4);
    int off = key * 128 + ((dq * 8) ^ ((key & 7) << 4));
    *(u16x4*)((char*)Th + off) = a;
    *(u16x4*)((char*)Tl + off) = bb;
  }
  __syncthreads();
  int d = t >> 2, kq = t & 3;
  u16 outh[32], outl[32];
#pragma unroll
  for (int jj = 0; jj < 32; jj++) {
    int key = kq * 32 + jj;
    int off = key * 128 + ((d * 2) ^ ((key & 7) << 4));
    outh[jj] = *(const u16*)((const char*)Th + off);
    outl[jj] = *(const u16*)((const char*)Tl + off);
  }
  u16* dsth = vth + (((size_t)gg * 64) + d) * S_LEN + kb * 128 + kq * 32;
  u16* dstl = vtl + (((size_t)gg * 64) + d) * S_LEN + kb * 128 + kq * 32;
#pragma unroll
  for (int q4 = 0; q4 < 8; q4++) {
    u16x4 a = {outh[q4 * 4], outh[q4 * 4 + 1], outh[q4 * 4 + 2], outh[q4 * 4 + 3]};
    u16x4 bb = {outl[q4 * 4], outl[q4 * 4 + 1], outl[q4 * 4 + 2], outl[q4 * 4 + 3]};
    *(u16x4*)(dsth + q4 * 4) = a;
    *(u16x4*)(dstl + q4 * 4) = bb;
  }
}

// ---------------- MFMA flash attention, split-precision ----------------
__global__ __launch_bounds__(256) void k_attn_mfma(
    const u16* __restrict__ qhp, const u16* __restrict__ qlp,
    const u16* __restrict__ khp, const u16* __restrict__ klp,
    const u16* __restrict__ vthp, const u16* __restrict__ vtlp,
    const float* __restrict__ sinks,
    u16* __restrict__ oh, u16* __restrict__ ol) {
  int qt = blockIdx.x;   // 0..31
  int bh = blockIdx.y;   // b*16+h
  int h = bh & 15, b = bh >> 4;
  int kvg = b * NKV + (h >> 2);
  int qbase = qt * 64;
  int t = threadIdx.x, w = t >> 6, l = t & 63;
  int g = l >> 4, li = l & 15;

  __shared__ u16 Qh[4096], Ql[4096], Kh[4096], Kl[4096], Vh[4096], Vl[4096];
  __shared__ u16 Ph[4][1024], Pl[4][1024];

  {
    const u16* sh = qhp + (((size_t)bh * S_LEN) + qbase) * 64;
    const u16* sl = qlp + (((size_t)bh * S_LEN) + qbase) * 64;
#pragma unroll
    for (int p = 0; p < 2; p++) {
      int idx = p * 256 + t;
      int row = idx >> 3, seg = idx & 7;
      u32x4 a = *(const u32x4*)(sh + row * 64 + seg * 8);
      u32x4 bb = *(const u32x4*)(sl + row * 64 + seg * 8);
      int off = row * 128 + ((seg * 16) ^ ((row & 7) << 4));
      *(u32x4*)((char*)Qh + off) = a;
      *(u32x4*)((char*)Ql + off) = bb;
    }
  }

  float m_[4], lsum[4];
  f32x4 accv[4];
  float sk = sinks[h];
#pragma unroll
  for (int j = 0; j < 4; j++) { m_[j] = sk; lsum[j] = 1.0f; }
#pragma unroll
  for (int nt = 0; nt < 4; nt++) accv[nt] = (f32x4){0.f, 0.f, 0.f, 0.f};

  int j0s = qbase - WINSZ; if (j0s < 0) j0s = 0;
  const u16* khb = khp + ((size_t)kvg * S_LEN) * 64;
  const u16* klb = klp + ((size_t)kvg * S_LEN) * 64;
  const u16* vthb = vthp + ((size_t)kvg * 64) * S_LEN;
  const u16* vtlb = vtlp + ((size_t)kvg * 64) * S_LEN;

  for (int j0 = j0s; j0 <= qbase; j0 += 64) {
    __syncthreads();
#pragma unroll
    for (int p = 0; p < 2; p++) {
      int idx = p * 256 + t;
      int row = idx >> 3, seg = idx & 7;
      int off = row * 128 + ((seg * 16) ^ ((row & 7) << 4));
      *(u32x4*)((char*)Kh + off) = *(const u32x4*)(khb + ((size_t)(j0 + row)) * 64 + seg * 8);
      *(u32x4*)((char*)Kl + off) = *(const u32x4*)(klb + ((size_t)(j0 + row)) * 64 + seg * 8);
      *(u32x4*)((char*)Vh + off) = *(const u32x4*)(vthb + (size_t)row * S_LEN + j0 + seg * 8);
      *(u32x4*)((char*)Vl + off) = *(const u32x4*)(vtlb + (size_t)row * S_LEN + j0 + seg * 8);
    }
    __syncthreads();

    f32x4 S[4];
#pragma unroll
    for (int nt = 0; nt < 4; nt++) S[nt] = (f32x4){0.f, 0.f, 0.f, 0.f};
#pragma unroll
    for (int ks = 0; ks < 2; ks++) {
      int arow = w * 16 + li;
      int coff = ks * 64 + g * 16;
      int ao = arow * 128 + (coff ^ ((arow & 7) << 4));
      bf16x8 qah = *(const bf16x8*)((char*)Qh + ao);
      bf16x8 qal = *(const bf16x8*)((char*)Ql + ao);
#pragma unroll
      for (int nt = 0; nt < 4; nt++) {
        int brow = nt * 16 + li;
        int bo = brow * 128 + (coff ^ ((brow & 7) << 4));
        bf16x8 kbh = *(const bf16x8*)((char*)Kh + bo);
        bf16x8 kbl = *(const bf16x8*)((char*)Kl + bo);
        S[nt] = __builtin_amdgcn_mfma_f32_16x16x32_bf16(qah, kbh, S[nt], 0, 0, 0);
        S[nt] = __builtin_amdgcn_mfma_f32_16x16x32_bf16(qah, kbl, S[nt], 0, 0, 0);
        S[nt] = __builtin_amdgcn_mfma_f32_16x16x32_bf16(qal, kbh, S[nt], 0, 0, 0);
      }
    }

    float scj[4];
#pragma unroll
    for (int j = 0; j < 4; j++) {
      int q = qbase + w * 16 + g * 4 + j;
      float sv[4];
      float mx = -1e30f;
#pragma unroll
      for (int nt = 0; nt < 4; nt++) {
        int key = j0 + nt * 16 + li;
        bool ok = (key <= q) && (key > q - WINSZ);
        sv[nt] = ok ? S[nt][j] : -1e30f;
        mx = fmaxf(mx, sv[nt]);
      }
#pragma unroll
      for (int o = 1; o < 16; o <<= 1) mx = fmaxf(mx, __shfl_xor(mx, o));
      float mn = fmaxf(m_[j], mx);
      float sc = __expf(m_[j] - mn);
      float ps = 0.f;
      float pv[4];
#pragma unroll
      for (int nt = 0; nt < 4; nt++) { pv[nt] = __expf(sv[nt] - mn); ps += pv[nt]; }
#pragma unroll
      for (int o = 1; o < 16; o <<= 1) ps += __shfl_xor(ps, o);
      lsum[j] = lsum[j] * sc + ps;
      m_[j] = mn;
      scj[j] = sc;
      int prow = g * 4 + j;
#pragma unroll
      for (int nt = 0; nt < 4; nt++) {
        int pb = prow * 128 + ((nt * 32 + li * 2) ^ ((prow & 7) << 4));
        u16 hi = f2b(pv[nt]);
        *(u16*)((char*)Ph[w] + pb) = hi;
        *(u16*)((char*)Pl[w] + pb) = f2b(pv[nt] - b2f(hi));
      }
    }
#pragma unroll
    for (int nt = 0; nt < 4; nt++) {
      f32x4 a = accv[nt];
      a[0] *= scj[0]; a[1] *= scj[1]; a[2] *= scj[2]; a[3] *= scj[3];
      accv[nt] = a;
    }

#pragma unroll
    for (int ks = 0; ks < 2; ks++) {
      int coff = ks * 64 + g * 16;
      int pb = li * 128 + (coff ^ ((li & 7) << 4));
      bf16x8 pah = *(const bf16x8*)((char*)Ph[w] + pb);
      bf16x8 pal = *(const bf16x8*)((char*)Pl[w] + pb);
#pragma unroll
      for (int nt = 0; nt < 4; nt++) {
        int vrow = nt * 16 + li;
        int vo = vrow * 128 + (coff ^ ((vrow & 7) << 4));
        bf16x8 vbh = *(const bf16x8*)((char*)Vh + vo);
        bf16x8 vbl = *(const bf16x8*)((char*)Vl + vo);
        accv[nt] = __builtin_amdgcn_mfma_f32_16x16x32_bf16(pah, vbh, accv[nt], 0, 0, 0);
        accv[nt] = __builtin_amdgcn_mfma_f32_16x16x32_bf16(pah, vbl, accv[nt], 0, 0, 0);
        accv[nt] = __builtin_amdgcn_mfma_f32_16x16x32_bf16(pal, vbh, accv[nt], 0, 0, 0);
      }
    }
  }

  float inv[4];
#pragma unroll
  for (int j = 0; j < 4; j++) inv[j] = 1.0f / lsum[j];
#pragma unroll
  for (int nt = 0; nt < 4; nt++) {
#pragma unroll
    for (int j = 0; j < 4; j++) {
      float o = accv[nt][j] * inv[j];
      int token = b * S_LEN + qbase + w * 16 + g * 4 + j;
      size_t off = (size_t)token * (NH * HDIM) + h * 64 + nt * 16 + li;
      u16 hi = f2b(o);
      oh[off] = hi;
      ol[off] = f2b(o - b2f(hi));
    }
  }
}

// ---------------- routing part 1: rms(h1) -> mb bf16 + 4 gate logits --------
__global__ __launch_bounds__(256) void k_routing1(const float* __restrict__ h1,
                                                  const float* __restrict__ pw,
                                                  const float* __restrict__ gw,
                                                  u16* __restrict__ mb,
                                                  float* __restrict__ lgbuf) {
  int row = blockIdx.x;
  int t = threadIdx.x;
  int wid = t >> 6;
  const f32x4* xr = (const f32x4*)(h1 + (size_t)row * DMODEL);
  f32x4 v = xr[t];
  float ss = wave_sum(v.x * v.x + v.y * v.y + v.z * v.z + v.w * v.w);
  __shared__ float red[4];
  __shared__ float redp[4][4];
  if ((t & 63) == 0) red[wid] = ss;
  __syncthreads();
  float tot = red[0] + red[1] + red[2] + red[3];
  float r = rsqrtf(tot * (1.0f / DMODEL) + EPSV);
  f32x4 w4 = ((const f32x4*)pw)[t];
  float m0 = v.x * r * w4.x, m1 = v.y * r * w4.y, m2 = v.z * r * w4.z, m3 = v.w * r * w4.w;
  u16x4 hb; hb.x = f2b(m0); hb.y = f2b(m1); hb.z = f2b(m2); hb.w = f2b(m3);
  ((u16x4*)(mb + (size_t)row * DMODEL))[t] = hb;
#pragma unroll
  for (int e = 0; e < NEXP; e++) {
    f32x4 g4 = ((const f32x4*)(gw + (size_t)e * DMODEL))[t];
    float pe = wave_sum(m0 * g4.x + m1 * g4.y + m2 * g4.z + m3 * g4.w);
    if ((t & 63) == 0) redp[wid][e] = pe;
  }
  __syncthreads();
  if (t < NEXP) {
    float lg = redp[0][t] + redp[1][t] + redp[2][t] + redp[3][t];
    lgbuf[(size_t)row * NEXP + t] = lg;
  }
}

// ---------------- routing part 2: top2, weights, per-expert entry lists ------
// idxb entries: token*2 + slot (slot0 = top1, slot1 = top2)
__global__ __launch_bounds__(256) void k_route2(const float* __restrict__ lgbuf,
                                                float* __restrict__ wd,
                                                int* __restrict__ cnt,
                                                int* __restrict__ idxb) {
  __shared__ int lcnt[NEXP], gbase[NEXP];
  int t = threadIdx.x;
  int token = blockIdx.x * 256 + t;
  if (t < NEXP) lcnt[t] = 0;
  __syncthreads();
  f32x4 lgv = ((const f32x4*)lgbuf)[token];
  float lg[4] = {lgv.x, lgv.y, lgv.z, lgv.w};
  int i1 = 0;
#pragma unroll
  for (int e = 1; e < NEXP; e++) if (lg[e] > lg[i1]) i1 = e;
  int i2 = -1;
#pragma unroll
  for (int e = 0; e < NEXP; e++) if (e != i1 && (i2 < 0 || lg[e] > lg[i2])) i2 = e;
  float d = __expf(lg[i2] - lg[i1]);
  float w1 = 1.0f / (1.0f + d);
  float w2 = 1.0f - w1;
  float wrow[4] = {0.f, 0.f, 0.f, 0.f};
  wrow[i1] = w1; wrow[i2] = w2;
  ((f32x4*)wd)[token] = (f32x4){wrow[0], wrow[1], wrow[2], wrow[3]};
  int r1 = atomicAdd(&lcnt[i1], 1);
  int r2 = atomicAdd(&lcnt[i2], 1);
  __syncthreads();
  if (t < NEXP) gbase[t] = atomicAdd(&cnt[t], lcnt[t]);
  __syncthreads();
  idxb[i1 * NTOK + gbase[i1] + r1] = token * 2;
  idxb[i2 * NTOK + gbase[i2] + r2] = token * 2 + 1;
}

// ------- routing part 3: concat list (256-aligned segs) + shared segment -----
// idxcat entry: token*4 + slot, slot in {0,1,2}; -1 = pad
__global__ __launch_bounds__(256) void k_route3(const int* __restrict__ cnt,
                                                const int* __restrict__ idxb,
                                                const float* __restrict__ wd,
                                                int* __restrict__ idxcat,
                                                float* __restrict__ wcat,
                                                int* __restrict__ pref) {
  int i = blockIdx.x * 256 + threadIdx.x;
  int c0 = cnt[0], c1 = cnt[1], c2 = cnt[2], c3 = cnt[3];
  int p1 = (c0 + 255) & ~255;
  int p2 = p1 + ((c1 + 255) & ~255);
  int p3 = p2 + ((c2 + 255) & ~255);
  int p4 = p3 + ((c3 + 255) & ~255);
  int p5 = p4 + NTOK;
  if (i == 0) {
    pref[0] = 0; pref[1] = p1; pref[2] = p2; pref[3] = p3; pref[4] = p4; pref[5] = p5;
  }
  if (i >= CATMAX) return;
  if (i >= p5) { idxcat[i] = -1; wcat[i] = 0.f; return; }
  if (i >= p4) {  // shared segment: all tokens, slot 2, weight 1
    idxcat[i] = (i - p4) * 4 + 2;
    wcat[i] = 1.0f;
    return;
  }
  int e, base, cn;
  if (i < p1) { e = 0; base = 0; cn = c0; }
  else if (i < p2) { e = 1; base = p1; cn = c1; }
  else if (i < p3) { e = 2; base = p2; cn = c2; }
  else { e = 3; base = p3; cn = c3; }
  int j = i - base;
  if (j < cn) {
    int entry = idxb[e * NTOK + j];
    idxcat[i] = (entry >> 1) * 4 + (entry & 1);
    wcat[i] = wd[(size_t)(entry >> 1) * NEXP + e];
  } else {
    idxcat[i] = -1;
    wcat[i] = 0.f;
  }
}

// ========== fused gate+up: 256x128 double-buffered GEMM (r6-proven) ==========
// 512 threads = 8 waves (2 wm x 4 wn); BK=64; T2 swizzle (seg ^= row&7) via
// pre-swizzled global source + swizzled ds_read; T1 XCD block relabel.
__global__ __launch_bounds__(512, 2) void k256gu(
    const u16* __restrict__ A, const u16* __restrict__ B1e,
    const u16* __restrict__ B2e,
    const int* __restrict__ idxcat, const int* __restrict__ pref,
    u16* __restrict__ actout) {
  __shared__ u16 As[2][256 * 64];
  __shared__ u16 Bs[2][128 * 64];
  __shared__ u16 Bus[2][128 * 64];
  int nwg = gridDim.x * gridDim.y;
  int swzid = xcd_swz(blockIdx.y * gridDim.x + blockIdx.x, nwg);
  int tn = swzid % gridDim.x, tm = swzid / gridDim.x;
  int Meff = pref[5];
  int r0 = tm * 256;
  if (r0 >= Meff) return;
  int e = (r0 < pref[1]) ? 0 : (r0 < pref[2]) ? 1 : (r0 < pref[3]) ? 2
          : (r0 < pref[4]) ? 3 : 4;
  const u16* B1 = B1e + (size_t)e * IDIM * DMODEL;
  const u16* B2 = B2e + (size_t)e * IDIM * DMODEL;

  int t = threadIdx.x;
  int w = t >> 6, l = t & 63;
  int wm = w >> 2, wn = w & 3;
  int li = l & 15, lh = l >> 4;

  size_t aOff[4];
  int seg = t & 7;
#pragma unroll
  for (int c = 0; c < 4; c++) {
    int r = c * 64 + (t >> 3);
    int swz = (seg ^ (r & 7)) * 8;
    int en = idxcat[r0 + r];
    int row = (en >= 0) ? (en >> 2) : 0;
    aOff[c] = (size_t)row * DMODEL + swz;
  }
  size_t bOff[2];
#pragma unroll
  for (int c = 0; c < 2; c++) {
    int r = c * 64 + (t >> 3);
    int swz = (seg ^ (r & 7)) * 8;
    bOff[c] = (size_t)(tn * 128 + r) * DMODEL + swz;
  }
  int wlds = w * 1024;

  f32x4 acc[8][2], accU[8][2];
#pragma unroll
  for (int f = 0; f < 8; f++)
#pragma unroll
    for (int cf = 0; cf < 2; cf++) {
      acc[f][cf] = (f32x4){0.f, 0.f, 0.f, 0.f};
      accU[f][cf] = (f32x4){0.f, 0.f, 0.f, 0.f};
    }

  auto stage = [&](int buf, int k0) {
    char* ab = (char*)As[buf];
#pragma unroll
    for (int c = 0; c < 4; c++) gld16(A + aOff[c] + k0, ab + c * 8192 + wlds);
    char* bb = (char*)Bs[buf];
#pragma unroll
    for (int c = 0; c < 2; c++) gld16(B1 + bOff[c] + k0, bb + c * 8192 + wlds);
    char* ub = (char*)Bus[buf];
#pragma unroll
    for (int c = 0; c < 2; c++) gld16(B2 + bOff[c] + k0, ub + c * 8192 + wlds);
  };

  stage(0, 0);
  __syncthreads();

  int NT = DMODEL >> 6;
  int cur = 0;
  for (int kt = 0; kt < NT; kt++) {
    if (kt + 1 < NT) stage(cur ^ 1, (kt + 1) << 6);
#pragma unroll
    for (int kk = 0; kk < 2; kk++) {
      bf16x8 af[8];
#pragma unroll
      for (int f = 0; f < 8; f++) {
        int r = wm * 128 + f * 16 + li;
        af[f] = *(const bf16x8*)((const char*)As[cur] + r * 128 +
                                 (((kk * 4 + lh) ^ (r & 7)) << 4));
      }
      bf16x8 bfr[2];
#pragma unroll
      for (int cf = 0; cf < 2; cf++) {
        int r = wn * 32 + cf * 16 + li;
        bfr[cf] = *(const bf16x8*)((const char*)Bs[cur] + r * 128 +
                                   (((kk * 4 + lh) ^ (r & 7)) << 4));
      }
#pragma unroll
      for (int f = 0; f < 8; f++)
#pragma unroll
        for (int cf = 0; cf < 2; cf++)
          acc[f][cf] = __builtin_amdgcn_mfma_f32_16x16x32_bf16(af[f], bfr[cf], acc[f][cf], 0, 0, 0);
      bf16x8 bu[2];
#pragma unroll
      for (int cf = 0; cf < 2; cf++) {
        int r = wn * 32 + cf * 16 + li;
        bu[cf] = *(const bf16x8*)((const char*)Bus[cur] + r * 128 +
                                  (((kk * 4 + lh) ^ (r & 7)) << 4));
      }
#pragma unroll
      for (int f = 0; f < 8; f++)
#pragma unroll
        for (int cf = 0; cf < 2; cf++)
          accU[f][cf] = __builtin_amdgcn_mfma_f32_16x16x32_bf16(af[f], bu[cf], accU[f][cf], 0, 0, 0);
    }
    __syncthreads();
    cur ^= 1;
  }

#pragma unroll
  for (int f = 0; f < 8; f++) {
#pragma unroll
    for (int j = 0; j < 4; j++) {
      int r = r0 + wm * 128 + f * 16 + lh * 4 + j;
#pragma unroll
      for (int cf = 0; cf < 2; cf++) {
        int c = tn * 128 + wn * 32 + cf * 16 + li;
        float g = acc[f][cf][j];
        float u = accU[f][cf][j];
        float gm = fminf(g, LIMV);
        float um = fminf(fmaxf(u, -LIMV), LIMV);
        float a = gm / (1.0f + __expf(-gm)) * um;
        actout[(size_t)r * IDIM + c] = f2b(a);
      }
    }
  }
}

// ========== down-proj: 256x128, BK=32, 2-buf, 48 KB LDS (2 blocks/CU) =======
// Fat-row LDS layout (r8-proven 0-conflict): two 64B tile-rows per 128B LDS
// row, pos = g ^ (fatrow&7); linear gld16 dest with inverse permutation on
// the global source; r6-proven 2-buf __syncthreads loop; T1 XCD relabel.
__global__ __launch_bounds__(512, 4) void k256d(
    const u16* __restrict__ A, const u16* __restrict__ B1e,
    const int* __restrict__ idxcat, const float* __restrict__ wcat,
    const int* __restrict__ pref,
    u16* __restrict__ y3) {
  __shared__ u16 As[2][256 * 32];   // 32 KB
  __shared__ u16 B1s[2][128 * 32];  // 16 KB
  int nwg = gridDim.x * gridDim.y;
  int swzid = xcd_swz(blockIdx.y * gridDim.x + blockIdx.x, nwg);
  int tn = swzid % gridDim.x, tm = swzid / gridDim.x;
  int Meff = pref[5];
  int r0 = tm * 256;
  if (r0 >= Meff) return;
  int e = (r0 < pref[1]) ? 0 : (r0 < pref[2]) ? 1 : (r0 < pref[3]) ? 2
          : (r0 < pref[4]) ? 3 : 4;
  const u16* B1 = B1e + (size_t)e * DMODEL * IDIM;

  int t = threadIdx.x;
  int w = t >> 6, l = t & 63;
  int wm = w >> 2, wn = w & 3;
  int li = l & 15, lh = l >> 4;

  // write-side (inverse fat-row permutation), A: 2 chunks, B: 1 chunk
  int g = (l & 7) ^ (l >> 3);
  int kchunk = g & 3;
  size_t aG[2];
#pragma unroll
  for (int c = 0; c < 2; c++) {
    int rA = c * 64 + w * 8 + (l >> 3) + 128 * (g >> 2);
    aG[c] = (size_t)(r0 + rA) * IDIM + kchunk * 8;
  }
  size_t bG;
  {
    int rB = w * 8 + (l >> 3) + 64 * (g >> 2);
    bG = (size_t)(tn * 128 + rB) * IDIM + kchunk * 8;
  }
  int wlds = w * 1024;

  // read-side LDS byte bases (XOR fat-row swizzle)
  int abase = li * 128 + (((wm * 4 + lh) ^ (li & 7)) << 4);
  int bbase = ((wn & 1) * 32 + li) * 128 + ((((wn >> 1) * 4 + lh) ^ (li & 7)) << 4);

  f32x4 acc[8][2];
#pragma unroll
  for (int f = 0; f < 8; f++)
#pragma unroll
    for (int cf = 0; cf < 2; cf++) acc[f][cf] = (f32x4){0.f, 0.f, 0.f, 0.f};

  auto stage = [&](int buf, int k0) {
    char* as = (char*)As[buf];
    gld16(A + aG[0] + k0, as + wlds);
    gld16(A + aG[1] + k0, as + 8192 + wlds);
    gld16(B1 + bG + k0, (char*)B1s[buf] + wlds);
  };

  stage(0, 0);
  __syncthreads();

  int NT = IDIM >> 5;  // 112
  int cur = 0;
  for (int kt = 0; kt < NT; kt++) {
    if (kt + 1 < NT) stage(cur ^ 1, (kt + 1) << 5);
    bf16x8 af[8];
#pragma unroll
    for (int f = 0; f < 8; f++)
      af[f] = *(const bf16x8*)((const char*)As[cur] + abase + f * 2048);
    bf16x8 b1f[2];
#pragma unroll
    for (int cf = 0; cf < 2; cf++)
      b1f[cf] = *(const bf16x8*)((const char*)B1s[cur] + bbase + cf * 2048);
#pragma unroll
    for (int f = 0; f < 8; f++)
#pragma unroll
      for (int cf = 0; cf < 2; cf++)
        acc[f][cf] = __builtin_amdgcn_mfma_f32_16x16x32_bf16(af[f], b1f[cf], acc[f][cf], 0, 0, 0);
    __syncthreads();
    cur ^= 1;
  }

#pragma unroll
  for (int f = 0; f < 8; f++) {
#pragma unroll
    for (int j = 0; j < 4; j++) {
      int r = r0 + wm * 128 + f * 16 + lh * 4 + j;
#pragma unroll
      for (int cf = 0; cf < 2; cf++) {
        int c = tn * 128 + wn * 32 + cf * 16 + li;
        int entry = idxcat[r];
        if (entry >= 0) {
          int tok = entry >> 2, slot = entry & 3;
          y3[((size_t)slot * NTOK + tok) * DMODEL + c] = f2b(wcat[r] * acc[f][cf][j]);
        }
      }
    }
  }
}

// ---------------- MFMA GEMM (split precision): C = A @ Bw^T ----------------
// 128x128 tile, BK=32, global_load_lds staging. Used for QKV / WO only.
constexpr int EPI_STORE = 0;  // outF[r*ldc + col0 + c] = v
constexpr int EPI_H1 = 1;     // outF[r*ldc+c] = v + addsrc[r*ldc+c]

template <int EPI>
__global__ __launch_bounds__(256, 2) void k_gemm(
    const u16* __restrict__ Ah, const u16* __restrict__ Al,
    const u16* __restrict__ Bh, const u16* __restrict__ Bl,
    int M, int N, int K, int lda, int ldb,
    float* __restrict__ outF, int ldc, int col0,
    const float* __restrict__ addsrc) {
  __shared__ u16 As[2 * 128 * 32];
  __shared__ u16 Bs[2 * 128 * 32];
  int tm = blockIdx.y, tn = blockIdx.x;
  int t = threadIdx.x;
  int w = t >> 6, l = t & 63;
  int wr = w >> 1, wc = w & 1;

  size_t a0 = (size_t)(tm * 128 + (t >> 2)) * lda + (t & 3) * 8;
  size_t a1 = a0 + (size_t)64 * lda;
  size_t b0 = (size_t)(tn * 128 + (t >> 2)) * ldb + (t & 3) * 8;
  size_t b1 = b0 + (size_t)64 * ldb;

  char* AsW0 = (char*)As + w * 1024;
  char* AsW1 = (char*)As + 4096 + w * 1024;
  char* BsW0 = (char*)Bs + w * 1024;
  char* BsW1 = (char*)Bs + 4096 + w * 1024;

  f32x4 acc[4][4];
#pragma unroll
  for (int i = 0; i < 4; i++)
#pragma unroll
    for (int j = 0; j < 4; j++) acc[i][j] = (f32x4){0.f, 0.f, 0.f, 0.f};

  int arow = wr * 64 + (l & 15);
  int brow = wc * 64 + (l & 15);
  int koff = (l >> 4) * 8;

  for (int k0 = 0; k0 < K; k0 += 32) {
    __syncthreads();
    gld16(Ah + a0 + k0, AsW0);
    gld16(Ah + a1 + k0, AsW1);
    gld16(Bh + b0 + k0, BsW0);
    gld16(Bh + b1 + k0, BsW1);
    gld16(Al + a0 + k0, AsW0 + 8192);
    gld16(Al + a1 + k0, AsW1 + 8192);
    gld16(Bl + b0 + k0, BsW0 + 8192);
    gld16(Bl + b1 + k0, BsW1 + 8192);
    __syncthreads();
    bf16x8 af[2][4], bf[2][4];
#pragma unroll
    for (int mm = 0; mm < 4; mm++) {
      af[0][mm] = *(const bf16x8*)&As[(arow + mm * 16) * 32 + koff];
      bf[0][mm] = *(const bf16x8*)&Bs[(brow + mm * 16) * 32 + koff];
      af[1][mm] = *(const bf16x8*)&As[128 * 32 + (arow + mm * 16) * 32 + koff];
      bf[1][mm] = *(const bf16x8*)&Bs[128 * 32 + (brow + mm * 16) * 32 + koff];
    }
#pragma unroll
    for (int mi = 0; mi < 4; mi++)
#pragma unroll
      for (int ni = 0; ni < 4; ni++) {
        acc[mi][ni] = __builtin_amdgcn_mfma_f32_16x16x32_bf16(af[0][mi], bf[0][ni], acc[mi][ni], 0, 0, 0);
        acc[mi][ni] = __builtin_amdgcn_mfma_f32_16x16x32_bf16(af[0][mi], bf[1][ni], acc[mi][ni], 0, 0, 0);
        acc[mi][ni] = __builtin_amdgcn_mfma_f32_16x16x32_bf16(af[1][mi], bf[0][ni], acc[mi][ni], 0, 0, 0);
      }
  }

  int rb = tm * 128 + wr * 64 + ((l >> 4) << 2);
  int cb = tn * 128 + wc * 64 + (l & 15);
#pragma unroll
  for (int mi = 0; mi < 4; mi++) {
#pragma unroll
    for (int j = 0; j < 4; j++) {
      int r = rb + mi * 16 + j;
#pragma unroll
      for (int ni = 0; ni < 4; ni++) {
        int c = cb + ni * 16;
        float v = acc[mi][ni][j];
        if constexpr (EPI == EPI_STORE) {
          outF[(size_t)r * ldc + col0 + c] = v;
        } else {
          size_t o = (size_t)r * ldc + c;
          outF[o] = v + addsrc[o];
        }
      }
    }
  }
}

// ---------------- final: out = h1 + y3[0] + y3[1] + y3[2] ----------------
__global__ __launch_bounds__(256) void k_final(const float* __restrict__ h1,
                                               const u16* __restrict__ y3,
                                               float* __restrict__ out) {
  int i = blockIdx.x * 256 + threadIdx.x;
  f32x4 a = ((const f32x4*)h1)[i];
  u16x4 s0 = ((const u16x4*)y3)[i];
  u16x4 s1 = ((const u16x4*)(y3 + (size_t)NTOK * DMODEL))[i];
  u16x4 s2 = ((const u16x4*)(y3 + (size_t)2 * NTOK * DMODEL))[i];
  f32x4 r = {a.x + b2f(s0.x) + b2f(s1.x) + b2f(s2.x),
             a.y + b2f(s0.y) + b2f(s1.y) + b2f(s2.y),
             a.z + b2f(s0.z) + b2f(s1.z) + b2f(s2.z),
             a.w + b2f(s0.w) + b2f(s1.w) + b2f(s2.w)};
  ((f32x4*)out)[i] = r;
}

// ---------------- host ----------------
extern "C" void kernel_launch(void* const* d_in, const int* in_sizes, int n_in,
                              void* d_out, int out_size, void* d_ws, size_t ws_size,
                              hipStream_t stream) {
  (void)in_sizes; (void)n_in; (void)out_size; (void)ws_size;
  const float* x = (const float*)d_in[0];
  const float* cosb = (const float*)d_in[1];
  const float* sinb = (const float*)d_in[2];
  const float* anw = (const float*)d_in[3];
  const float* pnw = (const float*)d_in[4];
  const float* qnw = (const float*)d_in[5];
  const float* knw = (const float*)d_in[6];
  const float* wq = (const float*)d_in[7];
  const float* wk = (const float*)d_in[8];
  const float* wv = (const float*)d_in[9];
  const float* wo = (const float*)d_in[10];
  const float* sinks = (const float*)d_in[11];
  const float* gw = (const float*)d_in[12];
  const float* egw = (const float*)d_in[13];
  const float* euw = (const float*)d_in[14];
  const float* edw = (const float*)d_in[15];
  const float* sgw = (const float*)d_in[16];
  const float* suw = (const float*)d_in[17];
  const float* sdw = (const float*)d_in[18];
  float* out = (float*)d_out;

  char* ws = (char*)d_ws;
  size_t off = 0;
  auto alloc = [&](size_t bytes) -> char* {
    char* p = ws + off;
    off += (bytes + 255) & ~(size_t)255;
    return p;
  };
  const size_t EW = (size_t)IDIM * DMODEL;  // 3,670,016 elems per expert matrix
  u16* wqkvh = (u16*)alloc((size_t)1536 * 1024 * 2);
  u16* wqkvl = (u16*)alloc((size_t)1536 * 1024 * 2);
  u16* woh = (u16*)alloc(1048576 * 2); u16* wol = (u16*)alloc(1048576 * 2);
  u16* egb5 = (u16*)alloc(5 * EW * 2);   // experts 0..3 + shared at slot 4
  u16* eub5 = (u16*)alloc(5 * EW * 2);
  u16* edb5 = (u16*)alloc(5 * EW * 2);
  float* h1 = (float*)alloc((size_t)NTOK * DMODEL * 4);
  u16* mb = (u16*)alloc((size_t)NTOK * DMODEL * 2);
  u16* y3 = (u16*)alloc((size_t)3 * NTOK * DMODEL * 2);
  float* wdbuf = (float*)alloc((size_t)NTOK * NEXP * 4);
  float* lgbuf = (float*)alloc((size_t)NTOK * NEXP * 4);
  int* cnt = (int*)alloc(256);
  int* idxb = (int*)alloc((size_t)NEXP * NTOK * 4);
  int* idxcat = (int*)alloc((size_t)CATMAX * 4);
  float* wcat = (float*)alloc((size_t)CATMAX * 4);
  int* pref = (int*)alloc(256);
  // big overlapped region (93.6 MB): attention-phase scratch, then MoE acts.
  char* regA = alloc((size_t)CATMAX * IDIM * 2);
  float* qkvb = (float*)regA;
  u16* qh_ = (u16*)(regA + 25165824);
  u16* ql_ = (u16*)(regA + 33554432);
  u16* kh_ = (u16*)(regA + 41943040);
  u16* kl_ = (u16*)(regA + 44040192);
  u16* vh_ = (u16*)(regA + 46137344);
  u16* vl_ = (u16*)(regA + 48234496);
  u16* vth_ = (u16*)(regA + 50331648);
  u16* vtl_ = (u16*)(regA + 52428800);
  u16* hinh = (u16*)(regA + 54525952);
  u16* hinl = (u16*)(regA + 62914560);
  u16* attnh = (u16*)(regA + 71303168);
  u16* attnl = (u16*)(regA + 79691776);
  u16* actcat = (u16*)regA;  // MoE phase: CATMAX x 3584 bf16 (whole region)

  k_init<<<1, 64, 0, stream>>>(cnt);

  CvtArgs ca;
  const float* srcs[10] = {wq, wk, wv, wo, egw, euw, edw, sgw, suw, sdw};
  u16* dhs[10] = {wqkvh, wqkvh + 1048576, wqkvh + 1310720, woh,
                  egb5, eub5, edb5, egb5 + 4 * EW, eub5 + 4 * EW, edb5 + 4 * EW};
  u16* dls[10] = {wqkvl, wqkvl + 1048576, wqkvl + 1310720, wol,
                  nullptr, nullptr, nullptr, nullptr, nullptr, nullptr};
  int ns[10] = {1048576, 262144, 262144, 1048576, 14680064, 14680064, 14680064,
                3670016, 3670016, 3670016};
  for (int i = 0; i < 10; i++) {
    ca.src[i] = srcs[i]; ca.dh[i] = dhs[i]; ca.dl[i] = dls[i]; ca.n4[i] = ns[i] / 4;
  }
  k_convert<<<dim3(2048, 10), 256, 0, stream>>>(ca);

  k_rms_split<<<NTOK, 256, 0, stream>>>(x, anw, hinh, hinl);

  // merged QKV projection (split precision), fp32 into qkvb (ldc=1536)
  k_gemm<EPI_STORE><<<dim3(12, 32), 256, 0, stream>>>(
      hinh, hinl, wqkvh, wqkvl, NTOK, 1536, 1024, 1024, 1024,
      qkvb, 1536, 0, nullptr);

  k_qkprep<<<NTOK, 256, 0, stream>>>(qkvb, cosb, sinb, qnw, knw,
                                     qh_, ql_, kh_, kl_, vh_, vl_);
  k_vtrans<<<dim3(16, 8), 256, 0, stream>>>(vh_, vl_, vth_, vtl_);
  k_attn_mfma<<<dim3(32, 32), 256, 0, stream>>>(qh_, ql_, kh_, kl_, vth_, vtl_,
                                                sinks, attnh, attnl);

  // out-proj + residual -> h1 (split precision)
  k_gemm<EPI_H1><<<dim3(8, 32), 256, 0, stream>>>(
      attnh, attnl, woh, wol, NTOK, 1024, 1024, 1024, 1024,
      h1, 1024, 0, x);

  k_routing1<<<NTOK, 256, 0, stream>>>(h1, pnw, gw, mb, lgbuf);
  k_route2<<<16, 256, 0, stream>>>(lgbuf, wdbuf, cnt, idxb);
  k_route3<<<CATMAX / 256, 256, 0, stream>>>(cnt, idxb, wdbuf, idxcat, wcat, pref);

  // fused gate+up (+SwiGLU) over concat list (experts + shared)
  k256gu<<<dim3(IDIM / 128, CATMAX / 256), 512, 0, stream>>>(
      mb, egb5, eub5, idxcat, pref, actcat);
  // down-proj + weighted scatter into y3 slots
  k256d<<<dim3(DMODEL / 128, CATMAX / 256), 512, 0, stream>>>(
      actcat, edb5, idxcat, wcat, pref, y3);

  k_final<<<4096, 256, 0, stream>>>(h1, y3, out);
}